// Round 2
// baseline (471.434 us; speedup 1.0000x reference)
//
#include <hip/hip_runtime.h>
#include <hip/hip_bf16.h>

// Shapes (fixed by the problem)
#define BATCH 256
#define F_DIM 2048
#define H_DIM 512
#define HH    256
#define NCLS  512
#define E_DIM 8

typedef __attribute__((ext_vector_type(8))) short  bf16x8;  // MFMA A/B frag (4 VGPRs)
typedef __attribute__((ext_vector_type(4))) float  f32x4;   // MFMA C/D frag
typedef __attribute__((ext_vector_type(4))) unsigned short u16x4;

__device__ __forceinline__ unsigned short f2bf(float x) {
    union { float f; unsigned int u; } v; v.f = x;
    unsigned int r = v.u + 0x7fffu + ((v.u >> 16) & 1u);  // RNE
    return (unsigned short)(r >> 16);
}

// ---------------------------------------------------------------------------
// Kernel A: stage-1 GEMM partials, no pre-transpose: B-frags load fp32 from Ws
// directly (8 scalar loads at 2KB stride, lanes coalesce over n) + on-the-fly
// bf16 cvt. 1024 wave-jobs = 16 mt x 8 ng x 8 ksplit. Barrier-free.
// partials[ks][256][512] fp32
// ---------------------------------------------------------------------------
__global__ __launch_bounds__(256) void k_gemm1(
    const float* __restrict__ features,        // [256][2048]
    const float* __restrict__ Ws,              // [2048][512]
    float* __restrict__ partials)              // [8][256][512]
{
    const int tid = threadIdx.x;
    const int lane = tid & 63;
    const int wave = tid >> 6;
    const int job = blockIdx.x * 4 + wave;     // 0..1023
    const int kidx = job & 7;                  // 8-way k-split
    const int ng  = (job >> 3) & 7;            // 8 col groups of 64
    const int mt  = job >> 6;                  // 16 row tiles of 16
    const int l15 = lane & 15, quad = lane >> 4;
    const int m0 = mt * 16, n0 = ng * 64, kb = kidx * 256;

    f32x4 z = {0.f, 0.f, 0.f, 0.f};
    f32x4 acc[4];
#pragma unroll
    for (int nf = 0; nf < 4; ++nf) acc[nf] = z;

#pragma unroll
    for (int ks = 0; ks < 8; ++ks) {
        const int kk = kb + ks * 32 + quad * 8;
        f32x4 a0 = *(const f32x4*)(features + (size_t)(m0 + l15) * F_DIM + kk);
        f32x4 a1 = *(const f32x4*)(features + (size_t)(m0 + l15) * F_DIM + kk + 4);
        bf16x8 aF;
#pragma unroll
        for (int j = 0; j < 4; ++j) { aF[j] = (short)f2bf(a0[j]); aF[4 + j] = (short)f2bf(a1[j]); }
#pragma unroll
        for (int nf = 0; nf < 4; ++nf) {
            bf16x8 bF;
#pragma unroll
            for (int j = 0; j < 8; ++j)
                bF[j] = (short)f2bf(Ws[(size_t)(kk + j) * H_DIM + n0 + nf * 16 + l15]);
            acc[nf] = __builtin_amdgcn_mfma_f32_16x16x32_bf16(aF, bF, acc[nf], 0, 0, 0);
        }
    }
    // C/D layout: col = lane&15, row = quad*4 + reg
    float* po = partials + (size_t)kidx * (BATCH * H_DIM);
#pragma unroll
    for (int nf = 0; nf < 4; ++nf)
#pragma unroll
        for (int r = 0; r < 4; ++r)
            po[(size_t)(m0 + quad * 4 + r) * H_DIM + n0 + nf * 16 + l15] = acc[nf][r];
}

// ---------------------------------------------------------------------------
// Kernel A2: reduce 8 partials + bias + relu -> shared bf16 [256][512]
// ---------------------------------------------------------------------------
__global__ __launch_bounds__(256) void k_reduce_relu(
    const float* __restrict__ partials, const float* __restrict__ bs,
    unsigned short* __restrict__ sharedA)
{
    const int idx = (blockIdx.x * 256 + threadIdx.x) * 4;  // over 256*512 elems
    f32x4 s = *(const f32x4*)(partials + idx);
#pragma unroll
    for (int p = 1; p < 8; ++p)
        s += *(const f32x4*)(partials + (size_t)p * (BATCH * H_DIM) + idx);
    s += *(const f32x4*)(bs + (idx & (H_DIM - 1)));
    u16x4 o;
#pragma unroll
    for (int j = 0; j < 4; ++j) {
        float v = s[j] > 0.f ? s[j] : 0.f;
        o[j] = f2bf(v);
    }
    *(u16x4*)(sharedA + idx) = o;
}

// ---------------------------------------------------------------------------
// Kernel B (main): one block (512 thr = 8 waves) per class. BARRIER-FREE K-loop:
// each wave is an independent 128x64 GEMM unit (mh = m-half, g = 64-col group),
// W1 fp32 loaded straight to registers (one k-step lookahead, full unroll ->
// fine-grained vmcnt pipelining), cvt to bf16 frags in-reg, MFMA from registers.
// W1[c] hits HBM exactly once. Single barrier only at the logits combine.
// ---------------------------------------------------------------------------
__global__ __launch_bounds__(512) void k_main(
    const unsigned short* __restrict__ sharedA,  // [256][512] bf16
    const float* __restrict__ W1,                // [C][512][256]
    const float* __restrict__ b1,                // [C][256]
    const float* __restrict__ W2,                // [C][256][8]
    const float* __restrict__ b2,                // [C][8]
    float* __restrict__ out)                     // gate_weights [256][512][8], then gate_logits
{
    const int c = blockIdx.x;
    const int tid = threadIdx.x;
    const int lane = tid & 63;
    const int wave = tid >> 6;          // 0..7
    const int l15 = lane & 15;
    const int quad = lane >> 4;
    const int g  = wave & 3;            // col group: 64 cols
    const int mh = wave >> 2;           // m half: 128 rows
    const int n0w = g * 64;
    const int m0w = mh * 128;

    const float* __restrict__ W1c = W1 + (size_t)c * (H_DIM * HH);

    __shared__ float slot[4][BATCH][E_DIM];   // per col-group logit partials, 32 KB

    f32x4 z = {0.f, 0.f, 0.f, 0.f};
    f32x4 acc[8][4];                    // [mf][nf] -> 128 VGPRs
#pragma unroll
    for (int mf = 0; mf < 8; ++mf)
#pragma unroll
        for (int nf = 0; nf < 4; ++nf) acc[mf][nf] = z;

    // rotating one-kstep-ahead register prefetch of B (raw fp32)
    float braw[2][32];
#pragma unroll
    for (int nf = 0; nf < 4; ++nf)
#pragma unroll
        for (int j = 0; j < 8; ++j)
            braw[0][nf * 8 + j] = W1c[(size_t)(quad * 8 + j) * HH + n0w + nf * 16 + l15];

#pragma unroll
    for (int ks = 0; ks < 16; ++ks) {
        const int cur = ks & 1;
        if (ks < 15) {
            const int k0n = (ks + 1) * 32;
#pragma unroll
            for (int nf = 0; nf < 4; ++nf)
#pragma unroll
                for (int j = 0; j < 8; ++j)
                    braw[cur ^ 1][nf * 8 + j] =
                        W1c[(size_t)(k0n + quad * 8 + j) * HH + n0w + nf * 16 + l15];
        }
        // convert current k-step's B to fragments
        bf16x8 bF[4];
#pragma unroll
        for (int nf = 0; nf < 4; ++nf)
#pragma unroll
            for (int j = 0; j < 8; ++j)
                bF[nf][j] = (short)f2bf(braw[cur][nf * 8 + j]);

        const int k0 = ks * 32 + quad * 8;
#pragma unroll
        for (int mf = 0; mf < 8; ++mf) {
            bf16x8 aF = *(const bf16x8*)(sharedA + (size_t)(m0w + mf * 16 + l15) * H_DIM + k0);
#pragma unroll
            for (int nf = 0; nf < 4; ++nf)
                acc[mf][nf] = __builtin_amdgcn_mfma_f32_16x16x32_bf16(aF, bF[nf], acc[mf][nf], 0, 0, 0);
        }
    }

    // ---- stage 3: h = relu(acc + b1), partial logits = h @ W2 over this wave's 64 cols
    float b1v[4];
    f32x4 w2a[4], w2b[4];
#pragma unroll
    for (int nf = 0; nf < 4; ++nf) {
        const int col = n0w + nf * 16 + l15;
        b1v[nf] = b1[(size_t)c * HH + col];
        w2a[nf] = *(const f32x4*)(W2 + ((size_t)c * HH + col) * E_DIM);
        w2b[nf] = *(const f32x4*)(W2 + ((size_t)c * HH + col) * E_DIM + 4);
    }

#pragma unroll
    for (int mf = 0; mf < 8; ++mf) {
        float part[4][E_DIM];
#pragma unroll
        for (int r = 0; r < 4; ++r)
#pragma unroll
            for (int e = 0; e < E_DIM; ++e) part[r][e] = 0.f;
#pragma unroll
        for (int nf = 0; nf < 4; ++nf) {
#pragma unroll
            for (int r = 0; r < 4; ++r) {
                float h = acc[mf][nf][r] + b1v[nf];
                h = h > 0.f ? h : 0.f;
                part[r][0] += h * w2a[nf][0]; part[r][1] += h * w2a[nf][1];
                part[r][2] += h * w2a[nf][2]; part[r][3] += h * w2a[nf][3];
                part[r][4] += h * w2b[nf][0]; part[r][5] += h * w2b[nf][1];
                part[r][6] += h * w2b[nf][2]; part[r][7] += h * w2b[nf][3];
            }
        }
        // reduce across the 16 lanes (cols) of each quad
#pragma unroll
        for (int r = 0; r < 4; ++r)
#pragma unroll
            for (int e = 0; e < E_DIM; ++e) {
                float v = part[r][e];
                v += __shfl_xor(v, 1, 16);
                v += __shfl_xor(v, 2, 16);
                v += __shfl_xor(v, 4, 16);
                v += __shfl_xor(v, 8, 16);
                part[r][e] = v;
            }
        if (l15 == 0) {
#pragma unroll
            for (int r = 0; r < 4; ++r) {
                const int row = m0w + mf * 16 + quad * 4 + r;
                f32x4 lo = {part[r][0], part[r][1], part[r][2], part[r][3]};
                f32x4 hi = {part[r][4], part[r][5], part[r][6], part[r][7]};
                *(f32x4*)(&slot[g][row][0]) = lo;
                *(f32x4*)(&slot[g][row][4]) = hi;
            }
        }
    }
    __syncthreads();   // the ONLY barrier

    // ---- combine col-group slots + softmax; thread t (<256) owns batch row t ----
    if (tid < BATCH) {
        f32x4 lg0 = *(f32x4*)(&slot[0][tid][0]);
        f32x4 lg1 = *(f32x4*)(&slot[0][tid][4]);
#pragma unroll
        for (int s = 1; s < 4; ++s) {
            lg0 += *(f32x4*)(&slot[s][tid][0]);
            lg1 += *(f32x4*)(&slot[s][tid][4]);
        }
        lg0 += *(const f32x4*)(b2 + (size_t)c * E_DIM);
        lg1 += *(const f32x4*)(b2 + (size_t)c * E_DIM + 4);

        float lg[8] = {lg0[0], lg0[1], lg0[2], lg0[3], lg1[0], lg1[1], lg1[2], lg1[3]};
        float mx = lg[0];
#pragma unroll
        for (int e = 1; e < 8; ++e) mx = lg[e] > mx ? lg[e] : mx;
        float ex[8], s = 0.f;
#pragma unroll
        for (int e = 0; e < 8; ++e) { ex[e] = __expf(lg[e] - mx); s += ex[e]; }
        const float inv = 1.f / s;

        const size_t ob = ((size_t)tid * NCLS + c) * E_DIM;
        f32x4 w0 = {ex[0] * inv, ex[1] * inv, ex[2] * inv, ex[3] * inv};
        f32x4 w1 = {ex[4] * inv, ex[5] * inv, ex[6] * inv, ex[7] * inv};
        *(f32x4*)(out + ob) = w0;
        *(f32x4*)(out + ob + 4) = w1;
        const size_t lbase = (size_t)BATCH * NCLS * E_DIM;
        f32x4 o0 = {lg[0], lg[1], lg[2], lg[3]};
        f32x4 o1 = {lg[4], lg[5], lg[6], lg[7]};
        *(f32x4*)(out + lbase + ob) = o0;
        *(f32x4*)(out + lbase + ob + 4) = o1;
    }
}

// ---------------------------------------------------------------------------
extern "C" void kernel_launch(void* const* d_in, const int* in_sizes, int n_in,
                              void* d_out, int out_size, void* d_ws, size_t ws_size,
                              hipStream_t stream) {
    const float* features = (const float*)d_in[0];  // [256][2048]
    const float* Ws       = (const float*)d_in[1];  // [2048][512]
    const float* bs       = (const float*)d_in[2];  // [512]
    const float* W1       = (const float*)d_in[3];  // [512][512][256]
    const float* b1       = (const float*)d_in[4];  // [512][256]
    const float* W2       = (const float*)d_in[5];  // [512][256][8]
    const float* b2       = (const float*)d_in[6];  // [512][8]
    float* out = (float*)d_out;

    char* ws = (char*)d_ws;
    float*          parts   = (float*)ws;                          // 8*256*512*4 = 4 MB
    unsigned short* sharedA = (unsigned short*)(ws + 4 * 1048576); // 256*512*2   = 256 KB

    hipLaunchKernelGGL(k_gemm1,       dim3(256), dim3(256), 0, stream, features, Ws, parts);
    hipLaunchKernelGGL(k_reduce_relu, dim3(128), dim3(256), 0, stream, parts, bs, sharedA);
    hipLaunchKernelGGL(k_main,        dim3(NCLS), dim3(512), 0, stream, sharedA, W1, b1, W2, b2, out);
}

// Round 3
// 454.941 us; speedup vs baseline: 1.0363x; 1.0363x over previous
//
#include <hip/hip_runtime.h>
#include <hip/hip_bf16.h>

// Shapes (fixed by the problem)
#define BATCH 256
#define F_DIM 2048
#define H_DIM 512
#define HH    256
#define NCLS  512
#define E_DIM 8

typedef __attribute__((ext_vector_type(8))) short  bf16x8;  // MFMA A/B frag (4 VGPRs)
typedef __attribute__((ext_vector_type(4))) float  f32x4;   // MFMA C/D frag
typedef __attribute__((ext_vector_type(4))) unsigned short u16x4;

__device__ __forceinline__ unsigned short f2bf(float x) {
    union { float f; unsigned int u; } v; v.f = x;
    unsigned int r = v.u + 0x7fffu + ((v.u >> 16) & 1u);  // RNE
    return (unsigned short)(r >> 16);
}

// ---------------------------------------------------------------------------
// Kernel A: stage-1 GEMM partials (barrier-free, as round 2 — passed & small)
// partials[ks][256][512] fp32
// ---------------------------------------------------------------------------
__global__ __launch_bounds__(256) void k_gemm1(
    const float* __restrict__ features,        // [256][2048]
    const float* __restrict__ Ws,              // [2048][512]
    float* __restrict__ partials)              // [8][256][512]
{
    const int tid = threadIdx.x;
    const int lane = tid & 63;
    const int wave = tid >> 6;
    const int job = blockIdx.x * 4 + wave;     // 0..1023
    const int kidx = job & 7;
    const int ng  = (job >> 3) & 7;
    const int mt  = job >> 6;
    const int l15 = lane & 15, quad = lane >> 4;
    const int m0 = mt * 16, n0 = ng * 64, kb = kidx * 256;

    f32x4 z = {0.f, 0.f, 0.f, 0.f};
    f32x4 acc[4];
#pragma unroll
    for (int nf = 0; nf < 4; ++nf) acc[nf] = z;

#pragma unroll
    for (int ks = 0; ks < 8; ++ks) {
        const int kk = kb + ks * 32 + quad * 8;
        f32x4 a0 = *(const f32x4*)(features + (size_t)(m0 + l15) * F_DIM + kk);
        f32x4 a1 = *(const f32x4*)(features + (size_t)(m0 + l15) * F_DIM + kk + 4);
        bf16x8 aF;
#pragma unroll
        for (int j = 0; j < 4; ++j) { aF[j] = (short)f2bf(a0[j]); aF[4 + j] = (short)f2bf(a1[j]); }
#pragma unroll
        for (int nf = 0; nf < 4; ++nf) {
            bf16x8 bF;
#pragma unroll
            for (int j = 0; j < 8; ++j)
                bF[j] = (short)f2bf(Ws[(size_t)(kk + j) * H_DIM + n0 + nf * 16 + l15]);
            acc[nf] = __builtin_amdgcn_mfma_f32_16x16x32_bf16(aF, bF, acc[nf], 0, 0, 0);
        }
    }
    float* po = partials + (size_t)kidx * (BATCH * H_DIM);
#pragma unroll
    for (int nf = 0; nf < 4; ++nf)
#pragma unroll
        for (int r = 0; r < 4; ++r)
            po[(size_t)(m0 + quad * 4 + r) * H_DIM + n0 + nf * 16 + l15] = acc[nf][r];
}

// ---------------------------------------------------------------------------
// Kernel A2: reduce 8 partials + bias + relu -> shared bf16 [256][512]
// ---------------------------------------------------------------------------
__global__ __launch_bounds__(256) void k_reduce_relu(
    const float* __restrict__ partials, const float* __restrict__ bs,
    unsigned short* __restrict__ sharedA)
{
    const int idx = (blockIdx.x * 256 + threadIdx.x) * 4;
    f32x4 s = *(const f32x4*)(partials + idx);
#pragma unroll
    for (int p = 1; p < 8; ++p)
        s += *(const f32x4*)(partials + (size_t)p * (BATCH * H_DIM) + idx);
    s += *(const f32x4*)(bs + (idx & (H_DIM - 1)));
    u16x4 o;
#pragma unroll
    for (int j = 0; j < 4; ++j) {
        float v = s[j] > 0.f ? s[j] : 0.f;
        o[j] = f2bf(v);
    }
    *(u16x4*)(sharedA + idx) = o;
}

// ---------------------------------------------------------------------------
// Kernel B (main): block = (class c, col-quarter q). 256 thr = 4 waves,
// each wave 64 rows x 64 cols (acc[4][4] = 64 AGPR -> 3 blocks/CU).
// Double-buffered LDS, ONE barrier per BK=64 chunk, ordered so W1 loads are
// issued right after a barrier and consumed before the next one (never
// drained by the barrier's vmcnt(0)). W1 read from HBM exactly once (disjoint
// col slices). Partial logits go to part4[q][c][b][e] with plain stores.
// ---------------------------------------------------------------------------
__global__ __launch_bounds__(256, 3) void k_main(
    const unsigned short* __restrict__ sharedA,  // [256][512] bf16
    const float* __restrict__ W1,                // [C][512][256]
    const float* __restrict__ b1,                // [C][256]
    const float* __restrict__ W2,                // [C][256][8]
    float* __restrict__ part4)                   // [4][C][256][8]
{
    const int c = blockIdx.x >> 2;
    const int q = blockIdx.x & 3;
    const int tid = threadIdx.x;
    const int lane = tid & 63;
    const int wave = tid >> 6;
    const int l15 = lane & 15;
    const int quad = lane >> 4;
    const int m0w = wave * 64;          // wave's 64-row slice
    const int colL = tid & 63;          // staging role: column within quarter
    const int kseg = tid >> 6;          // staging role: 16-k segment

    const float* __restrict__ W1cq = W1 + (size_t)c * (H_DIM * HH) + q * 64;

    __shared__ unsigned short buf[2][8 * 64 * 8];  // [kg][col][8] bf16, 8 KB each

    f32x4 z = {0.f, 0.f, 0.f, 0.f};
    f32x4 acc[4][4];
#pragma unroll
    for (int mf = 0; mf < 4; ++mf)
#pragma unroll
        for (int nf = 0; nf < 4; ++nf) acc[mf][nf] = z;

    // prologue: issue chunk 0 (16 scalar dwords, 256B-coalesced per inst)
    float rg[16];
#pragma unroll
    for (int j = 0; j < 16; ++j)
        rg[j] = W1cq[(size_t)(kseg * 16 + j) * HH + colL];

#pragma unroll
    for (int ch = 0; ch < 8; ++ch) {
        unsigned short* bp = &buf[ch & 1][0];
        // pack chunk ch into LDS (waits on rg loads issued last iteration;
        // they had the whole previous compute window in flight)
#pragma unroll
        for (int h = 0; h < 2; ++h) {
            bf16x8 v;
#pragma unroll
            for (int j = 0; j < 8; ++j) v[j] = (short)f2bf(rg[h * 8 + j]);
            const int kg = kseg * 2 + h;
            *(bf16x8*)(bp + ((kg * 64 + colL) << 3)) = v;
        }
        __syncthreads();  // the ONLY barrier per chunk (double-buffer proof: waves
                          // stay within one chunk of each other across barriers)
        // issue next chunk's loads — consumed before the NEXT barrier, so the
        // barrier drain never hits them; in flight across the compute below
        if (ch < 7) {
#pragma unroll
            for (int j = 0; j < 16; ++j)
                rg[j] = W1cq[(size_t)((ch + 1) * 64 + kseg * 16 + j) * HH + colL];
        }
        // compute chunk ch: 2 k-steps of 32
#pragma unroll
        for (int ks = 0; ks < 2; ++ks) {
            const int k0 = ch * 64 + ks * 32 + quad * 8;
            bf16x8 aF[4];
#pragma unroll
            for (int mf = 0; mf < 4; ++mf)
                aF[mf] = *(const bf16x8*)(sharedA + (size_t)(m0w + mf * 16 + l15) * H_DIM + k0);
#pragma unroll
            for (int nf = 0; nf < 4; ++nf) {
                bf16x8 bF = *(const bf16x8*)(bp + (((ks * 4 + quad) * 64 + nf * 16 + l15) << 3));
#pragma unroll
                for (int mf = 0; mf < 4; ++mf)
                    acc[mf][nf] = __builtin_amdgcn_mfma_f32_16x16x32_bf16(aF[mf], bF, acc[mf][nf], 0, 0, 0);
            }
        }
    }

    // ---- epilogue: h = relu(acc + b1), partial logits over this block's 64 cols
    const int cq = q * 64;
    float b1v[4];
    f32x4 w2a[4], w2b[4];
#pragma unroll
    for (int nf = 0; nf < 4; ++nf) {
        const int col = cq + nf * 16 + l15;
        b1v[nf] = b1[(size_t)c * HH + col];
        w2a[nf] = *(const f32x4*)(W2 + ((size_t)c * HH + col) * E_DIM);
        w2b[nf] = *(const f32x4*)(W2 + ((size_t)c * HH + col) * E_DIM + 4);
    }

#pragma unroll
    for (int mf = 0; mf < 4; ++mf) {
        float part[4][E_DIM];
#pragma unroll
        for (int r = 0; r < 4; ++r)
#pragma unroll
            for (int e = 0; e < E_DIM; ++e) part[r][e] = 0.f;
#pragma unroll
        for (int nf = 0; nf < 4; ++nf) {
#pragma unroll
            for (int r = 0; r < 4; ++r) {
                float h = acc[mf][nf][r] + b1v[nf];
                h = h > 0.f ? h : 0.f;
                part[r][0] += h * w2a[nf][0]; part[r][1] += h * w2a[nf][1];
                part[r][2] += h * w2a[nf][2]; part[r][3] += h * w2a[nf][3];
                part[r][4] += h * w2b[nf][0]; part[r][5] += h * w2b[nf][1];
                part[r][6] += h * w2b[nf][2]; part[r][7] += h * w2b[nf][3];
            }
        }
        // reduce across the 16 lanes (cols) of each quad
#pragma unroll
        for (int r = 0; r < 4; ++r)
#pragma unroll
            for (int e = 0; e < E_DIM; ++e) {
                float v = part[r][e];
                v += __shfl_xor(v, 1, 16);
                v += __shfl_xor(v, 2, 16);
                v += __shfl_xor(v, 4, 16);
                v += __shfl_xor(v, 8, 16);
                part[r][e] = v;
            }
        if (l15 == 0) {
#pragma unroll
            for (int r = 0; r < 4; ++r) {
                const int row = m0w + mf * 16 + quad * 4 + r;
                f32x4 lo = {part[r][0], part[r][1], part[r][2], part[r][3]};
                f32x4 hi = {part[r][4], part[r][5], part[r][6], part[r][7]};
                float* dst = part4 + (((size_t)q * NCLS + c) * BATCH + row) * E_DIM;
                *(f32x4*)dst = lo;
                *(f32x4*)(dst + 4) = hi;
            }
        }
    }
}

// ---------------------------------------------------------------------------
// Kernel C: combine quarters + b2 + softmax. Block per class, thread per row.
// ---------------------------------------------------------------------------
__global__ __launch_bounds__(256) void k_softmax(
    const float* __restrict__ part4,   // [4][C][256][8]
    const float* __restrict__ b2,      // [C][8]
    float* __restrict__ out)           // gate_weights [256][512][8], then gate_logits
{
    const int c = blockIdx.x;
    const int b = threadIdx.x;

    f32x4 lg0 = {0.f, 0.f, 0.f, 0.f}, lg1 = {0.f, 0.f, 0.f, 0.f};
#pragma unroll
    for (int qq = 0; qq < 4; ++qq) {
        const float* p = part4 + (((size_t)qq * NCLS + c) * BATCH + b) * E_DIM;
        lg0 += *(const f32x4*)p;
        lg1 += *(const f32x4*)(p + 4);
    }
    lg0 += *(const f32x4*)(b2 + (size_t)c * E_DIM);
    lg1 += *(const f32x4*)(b2 + (size_t)c * E_DIM + 4);

    float lg[8] = {lg0[0], lg0[1], lg0[2], lg0[3], lg1[0], lg1[1], lg1[2], lg1[3]};
    float mx = lg[0];
#pragma unroll
    for (int e = 1; e < 8; ++e) mx = lg[e] > mx ? lg[e] : mx;
    float ex[8], s = 0.f;
#pragma unroll
    for (int e = 0; e < 8; ++e) { ex[e] = __expf(lg[e] - mx); s += ex[e]; }
    const float inv = 1.f / s;

    const size_t ob = ((size_t)b * NCLS + c) * E_DIM;
    f32x4 w0 = {ex[0] * inv, ex[1] * inv, ex[2] * inv, ex[3] * inv};
    f32x4 w1 = {ex[4] * inv, ex[5] * inv, ex[6] * inv, ex[7] * inv};
    *(f32x4*)(out + ob) = w0;
    *(f32x4*)(out + ob + 4) = w1;
    const size_t lbase = (size_t)BATCH * NCLS * E_DIM;
    f32x4 o0 = {lg[0], lg[1], lg[2], lg[3]};
    f32x4 o1 = {lg[4], lg[5], lg[6], lg[7]};
    *(f32x4*)(out + lbase + ob) = o0;
    *(f32x4*)(out + lbase + ob + 4) = o1;
}

// ---------------------------------------------------------------------------
extern "C" void kernel_launch(void* const* d_in, const int* in_sizes, int n_in,
                              void* d_out, int out_size, void* d_ws, size_t ws_size,
                              hipStream_t stream) {
    const float* features = (const float*)d_in[0];  // [256][2048]
    const float* Ws       = (const float*)d_in[1];  // [2048][512]
    const float* bs       = (const float*)d_in[2];  // [512]
    const float* W1       = (const float*)d_in[3];  // [512][512][256]
    const float* b1       = (const float*)d_in[4];  // [512][256]
    const float* W2       = (const float*)d_in[5];  // [512][256][8]
    const float* b2       = (const float*)d_in[6];  // [512][8]
    float* out = (float*)d_out;

    char* ws = (char*)d_ws;
    // Overlay: parts (4 MB) occupies the start of part4's region (16 MB) —
    // parts is fully consumed by k_reduce_relu before k_main writes part4.
    float*          parts   = (float*)ws;                            // 8*256*512*4 = 4 MB
    float*          part4   = (float*)ws;                            // 4*512*256*8*4 = 16 MB
    unsigned short* sharedA = (unsigned short*)(ws + 16777216);      // 256*512*2 = 256 KB

    hipLaunchKernelGGL(k_gemm1,       dim3(256),  dim3(256), 0, stream, features, Ws, parts);
    hipLaunchKernelGGL(k_reduce_relu, dim3(128),  dim3(256), 0, stream, parts, bs, sharedA);
    hipLaunchKernelGGL(k_main,        dim3(2048), dim3(256), 0, stream, sharedA, W1, b1, W2, part4);
    hipLaunchKernelGGL(k_softmax,     dim3(NCLS), dim3(256), 0, stream, part4, b2, out);
}